// Round 5
// baseline (449.640 us; speedup 1.0000x reference)
//
#include <hip/hip_runtime.h>

// LocalAttention: B=4, N=4096, DIM=1024, H=16, HD=64, WINDOW=256, EXT=128
// R4 (resubmit after broker timeout): gemm_qkv gets an LDS-transposed epilogue
// (ushort8 coalesced stores), V-transpose fused into the V-block epilogue
// (transpose_v kernel deleted), SCALE folded into Q. Attention = R3 chunked
// two-pass (proven).

typedef __attribute__((ext_vector_type(8))) short short8;
typedef __attribute__((ext_vector_type(4))) float f32x4;
typedef __attribute__((ext_vector_type(8))) unsigned short ushort8v;
typedef __attribute__((ext_vector_type(4))) unsigned short ushort4v;
typedef __attribute__((ext_vector_type(4))) unsigned int uint4v;
typedef __attribute__((ext_vector_type(4))) _Float16 half4;

#define K_DIM 1024

__device__ __forceinline__ unsigned short f2bf(float f) {
  unsigned int u = __builtin_bit_cast(unsigned int, f);
  u += 0x7FFFu + ((u >> 16) & 1u);
  return (unsigned short)(u >> 16);
}
__device__ __forceinline__ unsigned short f2h(float f) {
  _Float16 h = (_Float16)f;
  return __builtin_bit_cast(unsigned short, h);
}
__device__ __forceinline__ void gload_lds(const unsigned short* g, unsigned short* l) {
  __builtin_amdgcn_global_load_lds((const __attribute__((address_space(1))) void*)g,
                                   (__attribute__((address_space(3))) void*)l, 16, 0, 0);
}

// ---------------- fp32 -> bf16 convert ----------------
__global__ __launch_bounds__(256) void convf2b(const float* __restrict__ src,
                                               unsigned short* __restrict__ dst, int n4) {
  int i = blockIdx.x * blockDim.x + threadIdx.x;
  if (i >= n4) return;
  f32x4 v = *(const f32x4*)(src + (size_t)i * 4);
  ushort4v o;
  o[0] = f2bf(v[0]); o[1] = f2bf(v[1]); o[2] = f2bf(v[2]); o[3] = f2bf(v[3]);
  *(ushort4v*)(dst + (size_t)i * 4) = o;
}

// ---------------- shared GEMM core: C(128x128) = A * Bw^T ----------------
__device__ __forceinline__ void gemm_core(const unsigned short* __restrict__ A,
                                          const unsigned short* __restrict__ Bw,
                                          unsigned short* As, unsigned short* Bs,
                                          int m0, int f0, int tid, f32x4 acc[4][4]) {
  const int lane = tid & 63;
  const int w = tid >> 6;
  const int wm = (tid >> 7) & 1;
  const int wn = (tid >> 6) & 1;
  const int q15 = lane & 15, quad = lane >> 4;
  const int sw = q15 & 3;
  for (int kk = 0; kk < K_DIM; kk += 32) {
#pragma unroll
    for (int r = 0; r < 2; ++r) {
      int c = tid + r * 256;
      int row = c >> 2, s = c & 3;
      int gs = s ^ (row & 3);
      const unsigned short* ga = A + (size_t)(m0 + row) * K_DIM + kk + gs * 8;
      const unsigned short* gb = Bw + (size_t)(f0 + row) * K_DIM + kk + gs * 8;
      unsigned short* la = As + (size_t)(w * 64 + r * 256) * 8;
      unsigned short* lb = Bs + (size_t)(w * 64 + r * 256) * 8;
      gload_lds(ga, la);
      gload_lds(gb, lb);
    }
    __syncthreads();
    short8 af[4], bf[4];
#pragma unroll
    for (int i = 0; i < 4; ++i)
      af[i] = *(const short8*)&As[(wm * 64 + i * 16 + q15) * 32 + (quad ^ sw) * 8];
#pragma unroll
    for (int j = 0; j < 4; ++j)
      bf[j] = *(const short8*)&Bs[(wn * 64 + j * 16 + q15) * 32 + (quad ^ sw) * 8];
#pragma unroll
    for (int i = 0; i < 4; ++i)
#pragma unroll
      for (int j = 0; j < 4; ++j)
        acc[i][j] = __builtin_amdgcn_mfma_f32_16x16x32_bf16(af[i], bf[j], acc[i][j], 0, 0, 0);
    __syncthreads();
  }
}

// ---------------- QKV GEMM + bias + LDS-transposed epilogue ----------------
// Q blocks: pre-scaled by 1/8, bf16 (bh,n,d). K blocks: bf16 (bh,n,d).
// V blocks: fp16, stored TRANSPOSED to (bh,d,n) directly.
#define ELD 136

__global__ __launch_bounds__(256) void gemm_qkv(const unsigned short* __restrict__ A,
                                                const unsigned short* __restrict__ Bw,
                                                const float* __restrict__ bias,
                                                unsigned short* __restrict__ q,
                                                unsigned short* __restrict__ k,
                                                unsigned short* __restrict__ vt) {
  __shared__ unsigned short smem[8704];        // staging 8192 shorts; epilogue 64x136
  unsigned short* As = smem;
  unsigned short* Bs = smem + 4096;
  int m0 = (blockIdx.x & 127) * 128;
  int f0 = (blockIdx.x >> 7) * 128;            // 24 f-tiles
  int tid = threadIdx.x;
  f32x4 acc[4][4] = {};
  gemm_core(A, Bw, As, Bs, m0, f0, tid, acc);

  int lane = tid & 63;
  int q15 = lane & 15, quad = lane >> 4;
  int wm = (tid >> 7) & 1, wn = (tid >> 6) & 1;
  int which = f0 >> 10;                        // block-uniform
  unsigned short* dst = (which == 0) ? q : k;
  unsigned short* E = smem;
  int bb = m0 >> 12;                           // tiles never cross batch boundary

#pragma unroll
  for (int half = 0; half < 2; ++half) {
    __syncthreads();
    if (wm == half) {
#pragma unroll
      for (int j = 0; j < 4; ++j) {
        int col = wn * 64 + j * 16 + q15;
        float bj = bias[f0 + col];
#pragma unroll
        for (int i = 0; i < 4; ++i)
#pragma unroll
          for (int r = 0; r < 4; ++r) {
            float val = acc[i][j][r] + bj;
            if (which == 0) val *= 0.125f;     // fold SCALE into Q
            E[(i * 16 + quad * 4 + r) * ELD + col] =
                (which == 2) ? f2h(val) : f2bf(val);
          }
      }
    }
    __syncthreads();
    if (which != 2) {
      // row-major coalesced store: thread -> (row, 32-col segment)
      int lr = tid >> 2, cs = (tid & 3) * 32;
      int m = m0 + half * 64 + lr;
      int n = m & 4095;
      int fg = f0 + cs;
      int hh = (fg >> 6) & 15, d0 = fg & 63;
      unsigned short* dp = dst + ((size_t)(bb * 16 + hh) * 4096 + n) * 64 + d0;
      const unsigned short* ep = &E[lr * ELD + cs];
#pragma unroll
      for (int ci = 0; ci < 4; ++ci)
        *(ushort8v*)(dp + ci * 8) = *(const ushort8v*)(ep + ci * 8);
    } else {
      // transposed store: thread -> (f col, 32-row n segment)
      int f = tid >> 1, nseg = (tid & 1) * 32;
      int fg = f0 + f;
      int hh = (fg >> 6) & 15, d = fg & 63;
      int n0g = (m0 & 4095) + half * 64 + nseg;
      ushort8v o[4];
#pragma unroll
      for (int jj = 0; jj < 32; ++jj)
        o[jj >> 3][jj & 7] = E[(nseg + jj) * ELD + f];
      unsigned short* vp = vt + ((size_t)(bb * 16 + hh) * 64 + d) * 4096 + n0g;
#pragma unroll
      for (int ci = 0; ci < 4; ++ci)
        *(ushort8v*)(vp + ci * 8) = o[ci];
    }
  }
}

// ---------------- proj GEMM + bias -> fp32 out ----------------
__global__ __launch_bounds__(256) void gemm_proj(const unsigned short* __restrict__ A,
                                                 const unsigned short* __restrict__ Bw,
                                                 const float* __restrict__ bias,
                                                 float* __restrict__ out) {
  __shared__ unsigned short smem[8192];
  unsigned short* As = smem;
  unsigned short* Bs = smem + 4096;
  int m0 = (blockIdx.x & 127) * 128;
  int f0 = (blockIdx.x >> 7) * 128;            // 8 f-tiles
  int tid = threadIdx.x;
  f32x4 acc[4][4] = {};
  gemm_core(A, Bw, As, Bs, m0, f0, tid, acc);
  int lane = tid & 63;
  int wm = (tid >> 7) & 1, wn = (tid >> 6) & 1;
#pragma unroll
  for (int j = 0; j < 4; ++j) {
    int f = f0 + wn * 64 + j * 16 + (lane & 15);
    float bj = bias[f];
#pragma unroll
    for (int i = 0; i < 4; ++i) {
#pragma unroll
      for (int r = 0; r < 4; ++r) {
        int m = m0 + wm * 64 + i * 16 + (lane >> 4) * 4 + r;
        out[(size_t)m * 1024 + f] = acc[i][j][r] + bj;
      }
    }
  }
}

// ---------------- windowed attention (R3 structure; Q pre-scaled) ----------
__global__ __launch_bounds__(256) void attn3(const unsigned short* __restrict__ Q,
                                             const unsigned short* __restrict__ Kb,
                                             const unsigned short* __restrict__ Vt,
                                             unsigned short* __restrict__ Ao) {
  __shared__ unsigned short lds2[2][8192];     // 2 x 16KB

  int bid = blockIdx.x;                        // 64 bh * 64 qblocks
  int qb = bid & 63;
  int bh = bid >> 6;
  int b = bh >> 4, h = bh & 15;
  int tid = threadIdx.x, lane = tid & 63, w = tid >> 6;
  int q0 = qb * 64 + w * 16;
  int g = qb >> 2;
  int kst = g * 256 - 128;
  const size_t base = (size_t)bh * 4096 * 64;
  const int q15 = lane & 15, quad = lane >> 4;

  short8 bq[2];
#pragma unroll
  for (int s = 0; s < 2; ++s)
    bq[s] = *(const short8*)&Q[base + (size_t)(q0 + q15) * 64 + s * 32 + quad * 8];

  half4 spk[32];
  float mx = -1e30f;

  auto stageK = [&](int c, int buf) {
    int kb = kst + c * 128;
    kb = min(max(kb, 0), 4096 - 128);
    const unsigned short* Kg = Kb + base + (size_t)kb * 64;
#pragma unroll
    for (int i = 0; i < 4; ++i) {
      int slot = tid + i * 256;
      int row = slot >> 3, s = slot & 7;
      int gs = s ^ (row & 7);
      gload_lds(Kg + (size_t)row * 64 + gs * 8, &lds2[buf][(w * 64 + i * 256) * 8]);
    }
  };

  stageK(0, 0);
#pragma unroll
  for (int c = 0; c < 4; ++c) {
    __syncthreads();
    if (c < 3) stageK(c + 1, (c + 1) & 1);
    const unsigned short* Kc = lds2[c & 1];
    int r7 = q15 & 7;
#pragma unroll
    for (int nt = 0; nt < 8; ++nt) {
      int t = c * 8 + nt;
      int ky = kst + c * 128 + nt * 16;
      bool valid = (ky >= 0) && (ky < 4096);
      if (valid) {
        int sg0 = quad ^ r7;
        const unsigned short* kr = &Kc[(nt * 16 + q15) * 64];
        short8 ak0 = *(const short8*)&kr[sg0 * 8];
        short8 ak1 = *(const short8*)&kr[(sg0 ^ 4) * 8];
        f32x4 sa = {0.f, 0.f, 0.f, 0.f};
        sa = __builtin_amdgcn_mfma_f32_16x16x32_bf16(ak0, bq[0], sa, 0, 0, 0);
        sa = __builtin_amdgcn_mfma_f32_16x16x32_bf16(ak1, bq[1], sa, 0, 0, 0);
        mx = fmaxf(mx, fmaxf(fmaxf(sa[0], sa[1]), fmaxf(sa[2], sa[3])));
        half4 pk;
        pk[0] = (_Float16)sa[0]; pk[1] = (_Float16)sa[1];
        pk[2] = (_Float16)sa[2]; pk[3] = (_Float16)sa[3];
        spk[t] = pk;
      } else {
        spk[t] = (half4){(_Float16)0.f, (_Float16)0.f, (_Float16)0.f, (_Float16)0.f};
      }
    }
  }
  mx = fmaxf(mx, __shfl_xor(mx, 16, 64));
  mx = fmaxf(mx, __shfl_xor(mx, 32, 64));

  auto stageV = [&](int c, int buf) {
    int kb = kst + c * 128;
    kb = min(max(kb, 0), 4096 - 128);
    const unsigned short* Vg = Vt + (size_t)bh * 64 * 4096 + kb;
#pragma unroll
    for (int i = 0; i < 4; ++i) {
      int slot = tid + i * 256;
      int d = slot >> 4, s = slot & 15;
      int gs = s ^ (d & 15);
      gload_lds(Vg + (size_t)d * 4096 + gs * 8, &lds2[buf][(w * 64 + i * 256) * 8]);
    }
  };

  float sum = 0.f;
  f32x4 oacc[4];
#pragma unroll
  for (int dt = 0; dt < 4; ++dt) oacc[dt] = (f32x4){0.f, 0.f, 0.f, 0.f};

  stageV(0, 0);
#pragma unroll
  for (int c = 0; c < 4; ++c) {
    __syncthreads();
    if (c < 3) stageV(c + 1, (c + 1) & 1);
    const unsigned short* Vc = lds2[c & 1];
#pragma unroll
    for (int nt = 0; nt < 8; ++nt) {
      int t = c * 8 + nt;
      int ky = kst + c * 128 + nt * 16;
      bool valid = (ky >= 0) && (ky < 4096);
      if (!valid) continue;
      half4 sp = spk[t];
      float p0 = __expf((float)sp[0] - mx);
      float p1 = __expf((float)sp[1] - mx);
      float p2 = __expf((float)sp[2] - mx);
      float p3 = __expf((float)sp[3] - mx);
      sum += (p0 + p1) + (p2 + p3);
      half4 pk;
      pk[0] = (_Float16)p0; pk[1] = (_Float16)p1;
      pk[2] = (_Float16)p2; pk[3] = (_Float16)p3;
      int sgb = 2 * nt + (quad >> 1);
      int eo = (quad & 1) * 4;
#pragma unroll
      for (int dt = 0; dt < 4; ++dt) {
        int d = dt * 16 + q15;
        half4 bv = *(const half4*)&Vc[d * 128 + ((sgb ^ q15) * 8) + eo];
        oacc[dt] = __builtin_amdgcn_mfma_f32_16x16x16f16(pk, bv, oacc[dt], 0, 0, 0);
      }
    }
  }
  sum += __shfl_xor(sum, 16, 64);
  sum += __shfl_xor(sum, 32, 64);
  float linv = 1.0f / sum;

  float li[4];
#pragma unroll
  for (int r = 0; r < 4; ++r) li[r] = __shfl(linv, quad * 4 + r, 64);
#pragma unroll
  for (int dt = 0; dt < 4; ++dt) {
#pragma unroll
    for (int r = 0; r < 4; ++r) {
      float o = oacc[dt][r] * li[r];
      Ao[(size_t)(b * 4096 + q0 + quad * 4 + r) * 1024 + h * 64 + dt * 16 + q15] = f2bf(o);
    }
  }
}

// ---------------- host ----------------
extern "C" void kernel_launch(void* const* d_in, const int* in_sizes, int n_in,
                              void* d_out, int out_size, void* d_ws, size_t ws_size,
                              hipStream_t stream) {
  const float* x = (const float*)d_in[0];
  const float* w_qkv = (const float*)d_in[1];
  const float* b_qkv = (const float*)d_in[2];
  const float* w_proj = (const float*)d_in[3];
  const float* b_proj = (const float*)d_in[4];
  float* out = (float*)d_out;

  unsigned short* ws = (unsigned short*)d_ws;
  unsigned short* xb = ws;                       // 16777216
  unsigned short* wqkvb = ws + 16777216;         // 3145728
  unsigned short* wprojb = ws + 19922944;        // 1048576
  unsigned short* qb = ws + 20971520;            // 16777216
  unsigned short* kb = ws + 37748736;            // 16777216
  unsigned short* vtb = ws + 54525952;           // 16777216 (fp16, transposed)
  unsigned short* attnb = ws + 71303168;         // 16777216

  convf2b<<<16384, 256, 0, stream>>>(x, xb, 16777216 / 4);
  convf2b<<<3072, 256, 0, stream>>>(w_qkv, wqkvb, 3145728 / 4);
  convf2b<<<1024, 256, 0, stream>>>(w_proj, wprojb, 1048576 / 4);
  gemm_qkv<<<128 * 24, 256, 0, stream>>>(xb, wqkvb, b_qkv, qb, kb, vtb);
  attn3<<<4096, 256, 0, stream>>>(qb, kb, vtb, attnb);
  gemm_proj<<<128 * 8, 256, 0, stream>>>(attnb, wprojb, b_proj, out);
}